// Round 1
// baseline (1201.140 us; speedup 1.0000x reference)
//
#include <hip/hip_runtime.h>

#define NPTS   16384
#define KCODES 8192
#define DDIM   256
#define HWSZ   1024
#define CHW    (DDIM * HWSZ)          // 262144
#define OUT_ELEMS 4194304
#define LOSS_OFF  OUT_ELEMS
#define IDX_OFF   (OUT_ELEMS + 1)

#define PT 32            // points per block
#define KT 256           // codes per pass
#define DK 32            // d-chunk staged in LDS
#define NPASS  (KCODES / KT)   // 32
#define NCHUNK (DDIM / DK)     // 8
#define XLD (DDIM + 4)   // 260: padded x row (float4-aligned, breaks column conflicts)
#define ELD (KT + 4)     // 260: padded transposed-e row

__launch_bounds__(256, 2)
__global__ void vq_kernel(const float* __restrict__ x,
                          const float* __restrict__ emb,
                          float* __restrict__ out)
{
    __shared__ float  ldsX[PT][XLD];    // 33280 B  x tile, full D
    __shared__ float  ldsET[DK][ELD];   // 33280 B  e chunk, transposed [d][k]
    __shared__ float  ldsSE[KT];        // per-code ||e||^2 for current pass
    __shared__ float  ldsS[PT];         // per-point ||x||^2
    __shared__ int    ldsI[PT];
    __shared__ float  ldsRD[32][PT];    // argmin reduce (also s partials)
    __shared__ int    ldsRI[32][PT];
    __shared__ double ldsL[4];

    const int t   = threadIdx.x;
    const int n0  = blockIdx.x * PT;
    const int b   = n0 / HWSZ;
    const int hw0 = n0 % HWSZ;
    const float* xbase = x + (size_t)b * CHW + hw0;

    // ---- stage x tile: ldsX[p][c] = x[b][c][hw0+p] ----
    {
        const int p  = t & 31;
        const int c0 = t >> 5;               // 0..7
        for (int i = 0; i < 32; ++i) {
            const int c = c0 * 32 + i;
            ldsX[p][c] = xbase[(size_t)c * HWSZ + p];
        }
    }
    ldsSE[t] = 0.0f;                          // own slot; read only by own thread pre-barrier
    __syncthreads();

    // ---- s[p] = sum_c x^2 (any fp32 order: constant-per-point error cancels in argmin) ----
    {
        const int p   = t & 31;
        const int seg = t >> 5;
        float a = 0.0f;
        for (int i = 0; i < 32; ++i) { float v = ldsX[p][seg * 32 + i]; a = fmaf(v, v, a); }
        ldsRD[seg][p] = a;
    }
    __syncthreads();
    if (t < PT) {
        float s = 0.0f;
        for (int g = 0; g < 8; ++g) s += ldsRD[g][t];
        ldsS[t] = s;
    }
    __syncthreads();

    const int kg    = t & 31;
    const int pg    = t >> 5;
    const int pbase = pg * 4;
    const int k4    = kg * 4;

    float s_reg[4];
    #pragma unroll
    for (int i = 0; i < 4; ++i) s_reg[i] = ldsS[pbase + i];

    float best_d[4] = {3.4e38f, 3.4e38f, 3.4e38f, 3.4e38f};
    int   best_i[4] = {0, 0, 0, 0};

    for (int kp = 0; kp < NPASS; ++kp) {
        const int kbase = kp * KT;
        float accL[4][4] = {{0.f}};
        float accH[4][4] = {{0.f}};

        for (int ch = 0; ch < NCHUNK; ++ch) {
            __syncthreads();   // prior readers of ldsET done
            // stage 256 codes x 32 d, transposed; coalesced float4 global reads
            {
                const float* src = emb + (size_t)kbase * DDIM + ch * DK;
                #pragma unroll
                for (int i = 0; i < 8; ++i) {
                    const int f  = t + i * 256;      // 0..2047
                    const int k  = f >> 3;           // code row 0..255
                    const int dq = (f & 7) * 4;      // 0..28
                    const float4 v = *(const float4*)(src + (size_t)k * DDIM + dq);
                    ldsET[dq + 0][k] = v.x;
                    ldsET[dq + 1][k] = v.y;
                    ldsET[dq + 2][k] = v.z;
                    ldsET[dq + 3][k] = v.w;
                }
            }
            __syncthreads();
            // ||e||^2 accumulation for this chunk (each thread owns code t)
            {
                float a = ldsSE[t];
                for (int d = 0; d < DK; ++d) { float e = ldsET[d][t]; a = fmaf(e, e, a); }
                ldsSE[t] = a;
            }
            // main FMA loop: 4 points x 8 codes per thread
            for (int cb = 0; cb < DK / 4; ++cb) {
                const int c = cb * 4;
                float4 xv[4];
                #pragma unroll
                for (int i = 0; i < 4; ++i)
                    xv[i] = *(const float4*)&ldsX[pbase + i][ch * DK + c];
                #pragma unroll
                for (int dd = 0; dd < 4; ++dd) {
                    const float4 eL = *(const float4*)&ldsET[c + dd][k4];
                    const float4 eH = *(const float4*)&ldsET[c + dd][k4 + 128];
                    #pragma unroll
                    for (int i = 0; i < 4; ++i) {
                        const float xs = ((const float*)&xv[i])[dd];
                        accL[i][0] = fmaf(xs, eL.x, accL[i][0]);
                        accL[i][1] = fmaf(xs, eL.y, accL[i][1]);
                        accL[i][2] = fmaf(xs, eL.z, accL[i][2]);
                        accL[i][3] = fmaf(xs, eL.w, accL[i][3]);
                        accH[i][0] = fmaf(xs, eH.x, accH[i][0]);
                        accH[i][1] = fmaf(xs, eH.y, accH[i][1]);
                        accH[i][2] = fmaf(xs, eH.z, accH[i][2]);
                        accH[i][3] = fmaf(xs, eH.w, accH[i][3]);
                    }
                }
            }
        }
        __syncthreads();   // ldsSE complete, all compute done
        // finalize: replicate fl(fl(s+se) - 2m); strictly ascending code index
        #pragma unroll
        for (int j = 0; j < 4; ++j) {           // low half first (smaller indices)
            const float se = ldsSE[k4 + j];
            const int   ki = kbase + k4 + j;
            #pragma unroll
            for (int i = 0; i < 4; ++i) {
                const float T = s_reg[i] + se;
                const float d = fmaf(-2.0f, accL[i][j], T);
                if (d < best_d[i]) { best_d[i] = d; best_i[i] = ki; }
            }
        }
        #pragma unroll
        for (int j = 0; j < 4; ++j) {           // high half
            const float se = ldsSE[k4 + 128 + j];
            const int   ki = kbase + 128 + k4 + j;
            #pragma unroll
            for (int i = 0; i < 4; ++i) {
                const float T = s_reg[i] + se;
                const float d = fmaf(-2.0f, accH[i][j], T);
                if (d < best_d[i]) { best_d[i] = d; best_i[i] = ki; }
            }
        }
        __syncthreads();   // finalize reads of ldsSE done before re-zero
        ldsSE[t] = 0.0f;
    }

    // ---- cross-thread argmin reduce (lexicographic: dist, then index) ----
    #pragma unroll
    for (int i = 0; i < 4; ++i) {
        ldsRD[kg][pbase + i] = best_d[i];
        ldsRI[kg][pbase + i] = best_i[i];
    }
    __syncthreads();
    if (t < PT) {
        float bd = ldsRD[0][t];
        int   bi = ldsRI[0][t];
        for (int g = 1; g < 32; ++g) {
            const float d2 = ldsRD[g][t];
            const int   i2 = ldsRI[g][t];
            if (d2 < bd || (d2 == bd && i2 < bi)) { bd = d2; bi = i2; }
        }
        ldsI[t] = bi;
        out[(size_t)IDX_OFF + n0 + t] = (float)bi;
    }
    __syncthreads();

    // ---- gather x_q, straight-through out, loss partial ----
    double lsum = 0.0;
    {
        const int p  = t & 31;
        const int cg = t >> 5;                  // 0..7
        const int row = ldsI[p];
        const float* erow = emb + (size_t)row * DDIM;
        float* obase = out + (size_t)b * CHW + hw0 + p;
        for (int q = 0; q < 8; ++q) {
            const int c = cg * 32 + q * 4;
            const float4 ev = *(const float4*)(erow + c);
            const float4 xv = *(const float4*)&ldsX[p][c];
            #pragma unroll
            for (int u = 0; u < 4; ++u) {
                const float e  = ((const float*)&ev)[u];
                const float xx = ((const float*)&xv)[u];
                const float diff = e - xx;               // fl(x_q - xt)
                obase[(size_t)(c + u) * HWSZ] = xx + diff; // replicate straight-through rounding
                lsum += (double)diff * (double)diff;
            }
        }
    }
    // loss reduce: wave butterfly -> LDS -> one float atomic
    #pragma unroll
    for (int off = 32; off > 0; off >>= 1)
        lsum += __shfl_xor(lsum, off);
    if ((t & 63) == 0) ldsL[t >> 6] = lsum;
    __syncthreads();
    if (t == 0) {
        const double tot = ldsL[0] + ldsL[1] + ldsL[2] + ldsL[3];
        atomicAdd(&out[LOSS_OFF], (float)(tot * (1.25 / 4194304.0)));
    }
}

extern "C" void kernel_launch(void* const* d_in, const int* in_sizes, int n_in,
                              void* d_out, int out_size, void* d_ws, size_t ws_size,
                              hipStream_t stream) {
    (void)in_sizes; (void)n_in; (void)ws_size; (void)d_ws; (void)out_size;
    const float* x   = (const float*)d_in[0];
    const float* emb = (const float*)d_in[1];
    float* out = (float*)d_out;
    // zero the loss accumulator slot (d_out is poisoned 0xAA before every launch)
    hipMemsetAsync((char*)d_out + (size_t)LOSS_OFF * sizeof(float), 0, sizeof(float), stream);
    vq_kernel<<<NPTS / PT, 256, 0, stream>>>(x, emb, out);
}